// Round 1
// baseline (850.794 us; speedup 1.0000x reference)
//
#include <hip/hip_runtime.h>

// ============================================================================
// Swin V2 block, round 1.
// Stages: [cvt weights->bf16, cpb table] -> qkv GEMM (gather-fused, bf16 MFMA)
//         -> attention (fp32, 1 wave per (window,head)) -> proj+LN+residual
//         -> fc1+silu -> fc2+LN+residual.
// MFMA layout assumptions (gfx950 16x16x32 bf16):
//   A: row = lane%16, k = 4*(lane/16) + {0..3} (elems 0-3) and +16 (elems 4-7)
//   B: col = lane%16, same k pattern
//   C/D: col = lane%16, row = 4*(lane/16) + reg    [verified per guide m89]
// LDS tiles stored k-permuted: col = 8*((k%16)/4) + 4*(k/16) + (k%4)
// so a fragment is one contiguous ds_read_b128 at [row][8*(lane/16)].
// ============================================================================

typedef unsigned short ushort_t;
using f32x4  = __attribute__((ext_vector_type(4))) float;
using short8 = __attribute__((ext_vector_type(8))) short;

#define M_TOK 100352   // 32 * 64 windows * 49 tokens

__device__ __forceinline__ ushort_t f2bf(float f) {
  union { float f; unsigned u; } v; v.f = f;
  unsigned r = v.u + 0x7fffu + ((v.u >> 16) & 1u);
  return (ushort_t)(r >> 16);
}
__device__ __forceinline__ float bf2f(ushort_t u) {
  union { unsigned u; float f; } v; v.u = ((unsigned)u) << 16;
  return v.f;
}

// windowed-token index m -> image row index (same map for gather and scatter)
__device__ __forceinline__ int img_pos(int m) {
  int win = m / 49, n = m - win * 49;
  int b = win >> 6, wi = win & 63;
  int nd = n / 7, nm = n - nd * 7;
  int hs = (wi >> 3) * 7 + nd;
  int ws = (wi & 7) * 7 + nm;
  int h = hs + 3; if (h >= 56) h -= 56;
  int w = ws + 3; if (w >= 56) w -= 56;
  return b * 3136 + h * 56 + w;
}

__device__ __forceinline__ int region3(int a) { return a < 49 ? 0 : (a < 53 ? 1 : 2); }

// ---------------------------------------------------------------------------
__global__ void cvt_kernel(const float* __restrict__ in, ushort_t* __restrict__ out, int n) {
  int i = blockIdx.x * 256 + threadIdx.x;
  if (i < n) out[i] = f2bf(in[i]);
}

// ---------------------------------------------------------------------------
// CPB: tab_s[e][head] = 16*sigmoid( relu(REL_TABLE[e] @ w1.T + b1) @ w2.T )
__global__ __launch_bounds__(256) void cpb_kernel(
    const float* __restrict__ w1, const float* __restrict__ b1,
    const float* __restrict__ w2, float* __restrict__ tab_s) {
  int e = blockIdx.x;            // 0..168
  int t = threadIdx.x;           // 0..255
  int i = e / 13, j = e - 13 * (e / 13);
  auto cval = [](int a) -> float {
    float r = (a - 6) * (8.0f / 6.0f);
    float v = log2f(fabsf(r) + 1.f) * (1.f / 3.f);
    return r < 0.f ? -v : v;
  };
  float ci = cval(i), cj = cval(j);
  float h = fmaxf(ci * w1[2 * t] + cj * w1[2 * t + 1] + b1[t], 0.f);
  __shared__ float red[256];
  for (int head = 0; head < 6; ++head) {
    red[t] = h * w2[head * 256 + t];
    __syncthreads();
    for (int st = 128; st > 0; st >>= 1) {
      if (t < st) red[t] += red[t + st];
      __syncthreads();
    }
    if (t == 0) tab_s[e * 6 + head] = 16.f / (1.f + __expf(-red[0]));
    __syncthreads();
  }
}

// ---------------------------------------------------------------------------
// GEMM, tile 128(M) x 64(N), K-step 32, 4 waves (2x2 of 64x32).
// MODE 0: qkv (A = x fp32 with window gather, bias = concat(q_bias,0,v_bias))
// MODE 1: fc1 (A = x1 fp32 natural, bias = b0, silu epilogue)
// out bf16 [M][NTOT]
template<int KTOT, int MODE>
__global__ __launch_bounds__(256) void gemm_tile64(
    const float* __restrict__ Af, const ushort_t* __restrict__ W,
    const float* __restrict__ b0, const float* __restrict__ b1,
    ushort_t* __restrict__ out, int NTOT) {
  __shared__ ushort_t Al[128][32];
  __shared__ ushort_t Bl[64][32];
  int t = threadIdx.x;
  int m0 = blockIdx.x * 128, n0 = blockIdx.y * 64;

  int arow = t >> 1;
  int akoff = (t & 1) << 4;       // 0 or 16
  int am = m0 + arow;
  const float* Arowp = (MODE == 0) ? (Af + (size_t)img_pos(am) * 192 + akoff)
                                   : (Af + (size_t)am * KTOT + akoff);
  int colA = akoff ? 4 : 0;

  int bn = t >> 2, cB = t & 3;
  const ushort_t* Brow = W + (size_t)(n0 + bn) * KTOT + (cB << 3);
  int colB = ((cB & 1) << 4) | ((cB >> 1) << 2);   // {0,16,4,20}

  int lane = t & 63, wid = t >> 6;
  int wm = wid >> 1, wn = wid & 1;
  int lr = lane & 15, lg = lane >> 4;

  f32x4 acc[4][2];
#pragma unroll
  for (int a = 0; a < 4; ++a)
#pragma unroll
    for (int b = 0; b < 2; ++b) acc[a][b] = (f32x4){0.f, 0.f, 0.f, 0.f};

  for (int kt = 0; kt < KTOT; kt += 32) {
    float4 a0 = *(const float4*)(Arowp + kt + 0);
    float4 a1 = *(const float4*)(Arowp + kt + 4);
    float4 a2 = *(const float4*)(Arowp + kt + 8);
    float4 a3 = *(const float4*)(Arowp + kt + 12);
    ushort4 bv0 = *(const ushort4*)(Brow + kt + 0);
    ushort4 bv1 = *(const ushort4*)(Brow + kt + 4);
    __syncthreads();
    ushort_t* Ar = &Al[arow][0];
    *(ushort4*)(Ar + colA +  0) = make_ushort4(f2bf(a0.x), f2bf(a0.y), f2bf(a0.z), f2bf(a0.w));
    *(ushort4*)(Ar + colA +  8) = make_ushort4(f2bf(a1.x), f2bf(a1.y), f2bf(a1.z), f2bf(a1.w));
    *(ushort4*)(Ar + colA + 16) = make_ushort4(f2bf(a2.x), f2bf(a2.y), f2bf(a2.z), f2bf(a2.w));
    *(ushort4*)(Ar + colA + 24) = make_ushort4(f2bf(a3.x), f2bf(a3.y), f2bf(a3.z), f2bf(a3.w));
    ushort_t* Br = &Bl[bn][0];
    *(ushort4*)(Br + colB + 0) = bv0;
    *(ushort4*)(Br + colB + 8) = bv1;
    __syncthreads();
    short8 af[4], bfv[2];
#pragma unroll
    for (int fm = 0; fm < 4; ++fm)
      af[fm] = *(const short8*)&Al[wm * 64 + fm * 16 + lr][lg * 8];
#pragma unroll
    for (int fn = 0; fn < 2; ++fn)
      bfv[fn] = *(const short8*)&Bl[wn * 32 + fn * 16 + lr][lg * 8];
#pragma unroll
    for (int fm = 0; fm < 4; ++fm)
#pragma unroll
      for (int fn = 0; fn < 2; ++fn)
        acc[fm][fn] = __builtin_amdgcn_mfma_f32_16x16x32_bf16(af[fm], bfv[fn], acc[fm][fn], 0, 0, 0);
  }
#pragma unroll
  for (int fm = 0; fm < 4; ++fm) {
#pragma unroll
    for (int fn = 0; fn < 2; ++fn) {
      int col = n0 + wn * 32 + fn * 16 + lr;
      float bias;
      if (MODE == 0) bias = (col < 192) ? b0[col] : ((col < 384) ? 0.f : b1[col - 384]);
      else           bias = b0[col];
#pragma unroll
      for (int r = 0; r < 4; ++r) {
        int row = m0 + wm * 64 + fm * 16 + lg * 4 + r;
        float v = acc[fm][fn][r] + bias;
        if (MODE == 1) v = v / (1.f + __expf(-v));   // silu
        out[(size_t)row * NTOT + col] = f2bf(v);
      }
    }
  }
}

// ---------------------------------------------------------------------------
// GEMM with full-row (N=192) tile + LayerNorm + residual epilogue.
// tile 128 x 192, 4 waves (2x2 of 64x96). A is bf16.
// MODE 0: proj  (A = attn_out windowed, scatter via img_pos, resid = x,  out = x1)
// MODE 1: fc2   (A = hmid natural,      direct,              resid = x1, out = d_out)
template<int KTOT, int MODE>
__global__ __launch_bounds__(256) void gemm_ln(
    const ushort_t* __restrict__ Ab, const ushort_t* __restrict__ W,
    const float* __restrict__ bias, const float* __restrict__ gamma,
    const float* __restrict__ beta, const float* __restrict__ resid,
    float* __restrict__ out) {
  __shared__ ushort_t Al[128][32];
  __shared__ ushort_t Bl[192][32];
  __shared__ float part[2][128][2];
  int t = threadIdx.x;
  int m0 = blockIdx.x * 128;
  int arow = t >> 1, akoff = (t & 1) << 4;
  const ushort_t* Arowp = Ab + (size_t)(m0 + arow) * KTOT + akoff;
  int colA = akoff ? 4 : 0;
  int lane = t & 63, wid = t >> 6;
  int wm = wid >> 1, wn = wid & 1;
  int lr = lane & 15, lg = lane >> 4;

  f32x4 acc[4][6];
#pragma unroll
  for (int a = 0; a < 4; ++a)
#pragma unroll
    for (int b = 0; b < 6; ++b) acc[a][b] = (f32x4){0.f, 0.f, 0.f, 0.f};

  for (int kt = 0; kt < KTOT; kt += 32) {
    ushort4 a0 = *(const ushort4*)(Arowp + kt + 0);
    ushort4 a1 = *(const ushort4*)(Arowp + kt + 4);
    ushort4 a2 = *(const ushort4*)(Arowp + kt + 8);
    ushort4 a3 = *(const ushort4*)(Arowp + kt + 12);
    ushort4 bq[3][2];
#pragma unroll
    for (int i = 0; i < 3; ++i) {
      int task = t + (i << 8);
      int bn = task >> 2, c = task & 3;
      const ushort_t* p = W + (size_t)bn * KTOT + kt + (c << 3);
      bq[i][0] = *(const ushort4*)p;
      bq[i][1] = *(const ushort4*)(p + 4);
    }
    __syncthreads();
    ushort_t* Ar = &Al[arow][0];
    *(ushort4*)(Ar + colA +  0) = a0;
    *(ushort4*)(Ar + colA +  8) = a1;
    *(ushort4*)(Ar + colA + 16) = a2;
    *(ushort4*)(Ar + colA + 24) = a3;
#pragma unroll
    for (int i = 0; i < 3; ++i) {
      int task = t + (i << 8);
      int bn = task >> 2, c = task & 3;
      int colB = ((c & 1) << 4) | ((c >> 1) << 2);
      ushort_t* Br = &Bl[bn][0];
      *(ushort4*)(Br + colB + 0) = bq[i][0];
      *(ushort4*)(Br + colB + 8) = bq[i][1];
    }
    __syncthreads();
    short8 af[4], bfv[6];
#pragma unroll
    for (int fm = 0; fm < 4; ++fm)
      af[fm] = *(const short8*)&Al[wm * 64 + fm * 16 + lr][lg * 8];
#pragma unroll
    for (int fn = 0; fn < 6; ++fn)
      bfv[fn] = *(const short8*)&Bl[wn * 96 + fn * 16 + lr][lg * 8];
#pragma unroll
    for (int fm = 0; fm < 4; ++fm)
#pragma unroll
      for (int fn = 0; fn < 6; ++fn)
        acc[fm][fn] = __builtin_amdgcn_mfma_f32_16x16x32_bf16(af[fm], bfv[fn], acc[fm][fn], 0, 0, 0);
  }
  // bias add + per-row LN partials (each wave covers 96 of 192 cols)
#pragma unroll
  for (int fm = 0; fm < 4; ++fm) {
#pragma unroll
    for (int r = 0; r < 4; ++r) {
      float s1 = 0.f, s2 = 0.f;
#pragma unroll
      for (int fn = 0; fn < 6; ++fn) {
        int col = wn * 96 + fn * 16 + lr;
        float v = acc[fm][fn][r] + bias[col];
        acc[fm][fn][r] = v;
        s1 += v; s2 += v * v;
      }
#pragma unroll
      for (int off = 1; off < 16; off <<= 1) {
        s1 += __shfl_xor(s1, off);
        s2 += __shfl_xor(s2, off);
      }
      if (lr == 0) {
        int lrow = wm * 64 + fm * 16 + lg * 4 + r;
        part[wn][lrow][0] = s1;
        part[wn][lrow][1] = s2;
      }
    }
  }
  __syncthreads();
#pragma unroll
  for (int fm = 0; fm < 4; ++fm) {
#pragma unroll
    for (int r = 0; r < 4; ++r) {
      int lrow = wm * 64 + fm * 16 + lg * 4 + r;
      float s1 = part[0][lrow][0] + part[1][lrow][0];
      float s2 = part[0][lrow][1] + part[1][lrow][1];
      float mean = s1 * (1.f / 192.f);
      float var  = s2 * (1.f / 192.f) - mean * mean;
      float rstd = rsqrtf(fmaxf(var, 0.f) + 1e-5f);
      int row = m0 + lrow;
      size_t obase = (MODE == 0) ? (size_t)img_pos(row) * 192 : (size_t)row * 192;
#pragma unroll
      for (int fn = 0; fn < 6; ++fn) {
        int col = wn * 96 + fn * 16 + lr;
        float v = acc[fm][fn][r];
        out[obase + col] = resid[obase + col] + (v - mean) * rstd * gamma[col] + beta[col];
      }
    }
  }
}

// ---------------------------------------------------------------------------
// Attention: one wave per (window, head). lane = query row (49 of 64 active).
// qkv bf16 [M_TOK][576]: q at col head*32, k at +192, v at +384.
__global__ __launch_bounds__(64) void attn_kernel(
    const ushort_t* __restrict__ qkv, const float* __restrict__ logit_scale,
    const float* __restrict__ tab_s, ushort_t* __restrict__ attn_out) {
  __shared__ float ks[49][36];
  __shared__ float vs[49][36];
  __shared__ float tab_l[169];
  int win = blockIdx.x;
  int head = blockIdx.y;
  int lane = threadIdx.x;
  int wi = win & 63;
  int wh0 = (wi >> 3) * 7, ww0 = (wi & 7) * 7;

  for (int u = lane; u < 169; u += 64) tab_l[u] = tab_s[u * 6 + head];

  size_t base = (size_t)win * 49 * 576 + head * 32;
  for (int u = lane; u < 196; u += 64) {     // 49 rows x 4 chunks of 8
    int r = u >> 2, d8 = (u & 3) << 3;
    const ushort_t* kp = qkv + base + (size_t)r * 576 + 192 + d8;
    ushort4 k0 = *(const ushort4*)kp,        k1 = *(const ushort4*)(kp + 4);
    ushort4 v0 = *(const ushort4*)(kp + 192), v1 = *(const ushort4*)(kp + 196);
    float* kr = &ks[r][d8];
    kr[0] = bf2f(k0.x); kr[1] = bf2f(k0.y); kr[2] = bf2f(k0.z); kr[3] = bf2f(k0.w);
    kr[4] = bf2f(k1.x); kr[5] = bf2f(k1.y); kr[6] = bf2f(k1.z); kr[7] = bf2f(k1.w);
    float* vr = &vs[r][d8];
    vr[0] = bf2f(v0.x); vr[1] = bf2f(v0.y); vr[2] = bf2f(v0.z); vr[3] = bf2f(v0.w);
    vr[4] = bf2f(v1.x); vr[5] = bf2f(v1.y); vr[6] = bf2f(v1.z); vr[7] = bf2f(v1.w);
  }

  float scale = __expf(fminf(logit_scale[head], 4.605170186f));  // ln(100)
  float q[32];
  if (lane < 49) {
    const ushort_t* qp = qkv + base + (size_t)lane * 576;
#pragma unroll
    for (int c8 = 0; c8 < 4; ++c8) {
      ushort4 a = *(const ushort4*)(qp + c8 * 8);
      ushort4 b = *(const ushort4*)(qp + c8 * 8 + 4);
      q[c8 * 8 + 0] = bf2f(a.x); q[c8 * 8 + 1] = bf2f(a.y);
      q[c8 * 8 + 2] = bf2f(a.z); q[c8 * 8 + 3] = bf2f(a.w);
      q[c8 * 8 + 4] = bf2f(b.x); q[c8 * 8 + 5] = bf2f(b.y);
      q[c8 * 8 + 6] = bf2f(b.z); q[c8 * 8 + 7] = bf2f(b.w);
    }
    float ss = 0.f;
#pragma unroll
    for (int d = 0; d < 32; ++d) ss += q[d] * q[d];
    float rq = scale / fmaxf(sqrtf(ss), 1e-12f);
#pragma unroll
    for (int d = 0; d < 32; ++d) q[d] *= rq;
  } else {
#pragma unroll
    for (int d = 0; d < 32; ++d) q[d] = 0.f;
  }
  __syncthreads();
  if (lane < 49) {                 // normalize K rows in LDS
    float ss = 0.f;
#pragma unroll
    for (int d = 0; d < 32; ++d) ss += ks[lane][d] * ks[lane][d];
    float rk = 1.f / fmaxf(sqrtf(ss), 1e-12f);
#pragma unroll
    for (int d = 0; d < 32; ++d) ks[lane][d] *= rk;
  }
  __syncthreads();

  int rd = lane / 7, rm = lane - 7 * (lane / 7);
  int gr = region3(wh0 + rd) * 3 + region3(ww0 + rm);

  float s[49];
#pragma unroll
  for (int j = 0; j < 49; ++j) {
    float a = 0.f;
    const float* kj = &ks[j][0];
#pragma unroll
    for (int d = 0; d < 32; ++d) a += q[d] * kj[d];
    int jd = j / 7, jm = j - 7 * (j / 7);
    int gj = region3(wh0 + jd) * 3 + region3(ww0 + jm);
    int idx = (rd - jd + 6) * 13 + (rm - jm + 6);
    s[j] = a + tab_l[idx] + (gr == gj ? 0.f : -100.f);
  }
  float mx = s[0];
#pragma unroll
  for (int j = 1; j < 49; ++j) mx = fmaxf(mx, s[j]);
  float sum = 0.f;
#pragma unroll
  for (int j = 0; j < 49; ++j) { s[j] = __expf(s[j] - mx); sum += s[j]; }
  float rs = 1.f / sum;

  float o[32];
#pragma unroll
  for (int d = 0; d < 32; ++d) o[d] = 0.f;
#pragma unroll
  for (int j = 0; j < 49; ++j) {
    float pj = s[j];
    const float* vj = &vs[j][0];
#pragma unroll
    for (int d = 0; d < 32; ++d) o[d] += pj * vj[d];
  }
  if (lane < 49) {
    ushort_t* op = attn_out + ((size_t)win * 49 + lane) * 192 + head * 32;
#pragma unroll
    for (int c = 0; c < 8; ++c) {
      *(ushort4*)(op + c * 4) = make_ushort4(
          f2bf(o[c * 4 + 0] * rs), f2bf(o[c * 4 + 1] * rs),
          f2bf(o[c * 4 + 2] * rs), f2bf(o[c * 4 + 3] * rs));
    }
  }
}

// ---------------------------------------------------------------------------
extern "C" void kernel_launch(void* const* d_in, const int* in_sizes, int n_in,
                              void* d_out, int out_size, void* d_ws, size_t ws_size,
                              hipStream_t stream) {
  (void)in_sizes; (void)n_in; (void)out_size; (void)ws_size;
  const float* x    = (const float*)d_in[0];
  const float* qkvw = (const float*)d_in[1];
  const float* qb   = (const float*)d_in[2];
  const float* vb   = (const float*)d_in[3];
  const float* ls   = (const float*)d_in[4];
  const float* cw1  = (const float*)d_in[5];
  const float* cb1  = (const float*)d_in[6];
  const float* cw2  = (const float*)d_in[7];
  const float* pw   = (const float*)d_in[8];
  const float* pb   = (const float*)d_in[9];
  const float* n1g  = (const float*)d_in[10];
  const float* n1b  = (const float*)d_in[11];
  const float* n2g  = (const float*)d_in[12];
  const float* n2b  = (const float*)d_in[13];
  const float* f1w  = (const float*)d_in[14];
  const float* f1b  = (const float*)d_in[15];
  const float* f2w  = (const float*)d_in[16];
  const float* f2b  = (const float*)d_in[17];
  float* out = (float*)d_out;

  char* ws = (char*)d_ws;
  ushort_t* wq_bf = (ushort_t*)ws;                 // 110592
  ushort_t* wp_bf = wq_bf + 110592;                // 36864
  ushort_t* w1_bf = wp_bf + 36864;                 // 147456
  ushort_t* w2_bf = w1_bf + 147456;                // 147456
  float*    tab_s = (float*)(w2_bf + 147456);      // 1014 floats
  const size_t OFF_BIG = 1 << 20;
  ushort_t* qkv_out = (ushort_t*)(ws + OFF_BIG);                           // 100352*576 bf16
  ushort_t* attn_o  = (ushort_t*)(ws + OFF_BIG + 115605504);               // 100352*192 bf16
  float*    x1      = (float*)   (ws + OFF_BIG + 115605504 + 38535168);    // 100352*192 f32
  ushort_t* hmid    = (ushort_t*)(ws + OFF_BIG);   // reuse qkv+attn: 100352*768 bf16 (exact fit)

  cvt_kernel<<<(110592 + 255) / 256, 256, 0, stream>>>(qkvw, wq_bf, 110592);
  cvt_kernel<<<(36864  + 255) / 256, 256, 0, stream>>>(pw,   wp_bf, 36864);
  cvt_kernel<<<(147456 + 255) / 256, 256, 0, stream>>>(f1w,  w1_bf, 147456);
  cvt_kernel<<<(147456 + 255) / 256, 256, 0, stream>>>(f2w,  w2_bf, 147456);
  cpb_kernel<<<169, 256, 0, stream>>>(cw1, cb1, cw2, tab_s);

  gemm_tile64<192, 0><<<dim3(784, 9), 256, 0, stream>>>(x, wq_bf, qb, vb, qkv_out, 576);
  attn_kernel<<<dim3(2048, 6), 64, 0, stream>>>(qkv_out, ls, tab_s, attn_o);
  gemm_ln<192, 0><<<784, 256, 0, stream>>>(attn_o, wp_bf, pb, n1g, n1b, x, x1);
  gemm_tile64<192, 1><<<dim3(784, 12), 256, 0, stream>>>(x1, w1_bf, f1b, nullptr, hmid, 768);
  gemm_ln<768, 1><<<784, 256, 0, stream>>>(hmid, w2_bf, f2b, n2g, n2b, x1, out);
}

// Round 2
// 733.074 us; speedup vs baseline: 1.1606x; 1.1606x over previous
//
#include <hip/hip_runtime.h>

// ============================================================================
// Swin V2 block, round 2.
// R1 post-mortem: attn_kernel = 366us of 850 (1-wave blocks, 228 VGPR, VALU 30%).
// Changes: (1) attn rewritten: 256 thr/block, thread=(query,8-dim chunk), keys
// partitioned across 4-lane groups (no per-key shuffles), P via LDS tile.
// (2) qkv/fc1 GEMM N-tile widened 64->192 (acc[4][6]) - 3x fewer A re-reads.
// MFMA layout (verified by R1 pass): A row=lane%16, k=4*(lane/16)+{0..3}(+16);
// C/D col=lane%16, row=4*(lane/16)+reg. LDS k-permuted col=8*((k%16)/4)+4*(k/16)+k%4.
// ============================================================================

typedef unsigned short ushort_t;
using f32x4  = __attribute__((ext_vector_type(4))) float;
using short8 = __attribute__((ext_vector_type(8))) short;

__device__ __forceinline__ ushort_t f2bf(float f) {
  union { float f; unsigned u; } v; v.f = f;
  unsigned r = v.u + 0x7fffu + ((v.u >> 16) & 1u);
  return (ushort_t)(r >> 16);
}
__device__ __forceinline__ float bf2f(ushort_t u) {
  union { unsigned u; float f; } v; v.u = ((unsigned)u) << 16;
  return v.f;
}

// windowed-token index m -> image row index (same map for gather and scatter)
__device__ __forceinline__ int img_pos(int m) {
  int win = m / 49, n = m - win * 49;
  int b = win >> 6, wi = win & 63;
  int nd = n / 7, nm = n - nd * 7;
  int hs = (wi >> 3) * 7 + nd;
  int ws = (wi & 7) * 7 + nm;
  int h = hs + 3; if (h >= 56) h -= 56;
  int w = ws + 3; if (w >= 56) w -= 56;
  return b * 3136 + h * 56 + w;
}

__device__ __forceinline__ int region3(int a) { return a < 49 ? 0 : (a < 53 ? 1 : 2); }

// ---------------------------------------------------------------------------
__global__ void cvt_kernel(const float* __restrict__ in, ushort_t* __restrict__ out, int n) {
  int i = blockIdx.x * 256 + threadIdx.x;
  if (i < n) out[i] = f2bf(in[i]);
}

// ---------------------------------------------------------------------------
// CPB: tab_s[e][head] = 16*sigmoid( relu(REL_TABLE[e] @ w1.T + b1) @ w2.T )
__global__ __launch_bounds__(256) void cpb_kernel(
    const float* __restrict__ w1, const float* __restrict__ b1,
    const float* __restrict__ w2, float* __restrict__ tab_s) {
  int e = blockIdx.x;            // 0..168
  int t = threadIdx.x;           // 0..255
  int i = e / 13, j = e - 13 * (e / 13);
  auto cval = [](int a) -> float {
    float r = (a - 6) * (8.0f / 6.0f);
    float v = log2f(fabsf(r) + 1.f) * (1.f / 3.f);
    return r < 0.f ? -v : v;
  };
  float ci = cval(i), cj = cval(j);
  float h = fmaxf(ci * w1[2 * t] + cj * w1[2 * t + 1] + b1[t], 0.f);
  __shared__ float red[256];
  for (int head = 0; head < 6; ++head) {
    red[t] = h * w2[head * 256 + t];
    __syncthreads();
    for (int st = 128; st > 0; st >>= 1) {
      if (t < st) red[t] += red[t + st];
      __syncthreads();
    }
    if (t == 0) tab_s[e * 6 + head] = 16.f / (1.f + __expf(-red[0]));
    __syncthreads();
  }
}

// ---------------------------------------------------------------------------
// GEMM, tile 128(M) x 192(N), K-step 32, 4 waves (2x2 of 64x96), fp32 A + cvt.
// MODE 0: qkv (A gathered via img_pos, bias = concat(q_bias,0,v_bias) indexed
//         by global col), out bf16 [M][576] at col slab blockIdx.y*192.
// MODE 1: fc1 (A natural, bias b0, silu epilogue), out bf16 [M][768].
template<int KTOT, int MODE>
__global__ __launch_bounds__(256) void gemm_n192(
    const float* __restrict__ Af, const ushort_t* __restrict__ W,
    const float* __restrict__ b0, const float* __restrict__ b1,
    ushort_t* __restrict__ out, int NTOT) {
  __shared__ ushort_t Al[128][32];
  __shared__ ushort_t Bl[192][32];
  int t = threadIdx.x;
  int m0 = blockIdx.x * 128, n0 = blockIdx.y * 192;

  int arow = t >> 1, akoff = (t & 1) << 4;
  int am = m0 + arow;
  const float* Arowp = (MODE == 0) ? (Af + (size_t)img_pos(am) * 192 + akoff)
                                   : (Af + (size_t)am * KTOT + akoff);
  int colA = akoff ? 4 : 0;

  int lane = t & 63, wid = t >> 6;
  int wm = wid >> 1, wn = wid & 1;
  int lr = lane & 15, lg = lane >> 4;

  f32x4 acc[4][6];
#pragma unroll
  for (int a = 0; a < 4; ++a)
#pragma unroll
    for (int b = 0; b < 6; ++b) acc[a][b] = (f32x4){0.f, 0.f, 0.f, 0.f};

  for (int kt = 0; kt < KTOT; kt += 32) {
    float4 a0 = *(const float4*)(Arowp + kt + 0);
    float4 a1 = *(const float4*)(Arowp + kt + 4);
    float4 a2 = *(const float4*)(Arowp + kt + 8);
    float4 a3 = *(const float4*)(Arowp + kt + 12);
    ushort4 bq[3][2];
#pragma unroll
    for (int i = 0; i < 3; ++i) {
      int task = t + (i << 8);
      int bn = task >> 2, c = task & 3;
      const ushort_t* p = W + (size_t)(n0 + bn) * KTOT + kt + (c << 3);
      bq[i][0] = *(const ushort4*)p;
      bq[i][1] = *(const ushort4*)(p + 4);
    }
    __syncthreads();
    ushort_t* Ar = &Al[arow][0];
    *(ushort4*)(Ar + colA +  0) = make_ushort4(f2bf(a0.x), f2bf(a0.y), f2bf(a0.z), f2bf(a0.w));
    *(ushort4*)(Ar + colA +  8) = make_ushort4(f2bf(a1.x), f2bf(a1.y), f2bf(a1.z), f2bf(a1.w));
    *(ushort4*)(Ar + colA + 16) = make_ushort4(f2bf(a2.x), f2bf(a2.y), f2bf(a2.z), f2bf(a2.w));
    *(ushort4*)(Ar + colA + 24) = make_ushort4(f2bf(a3.x), f2bf(a3.y), f2bf(a3.z), f2bf(a3.w));
#pragma unroll
    for (int i = 0; i < 3; ++i) {
      int task = t + (i << 8);
      int bn = task >> 2, c = task & 3;
      int colB = ((c & 1) << 4) | ((c >> 1) << 2);
      ushort_t* Br = &Bl[bn][0];
      *(ushort4*)(Br + colB + 0) = bq[i][0];
      *(ushort4*)(Br + colB + 8) = bq[i][1];
    }
    __syncthreads();
    short8 af[4], bfv[6];
#pragma unroll
    for (int fm = 0; fm < 4; ++fm)
      af[fm] = *(const short8*)&Al[wm * 64 + fm * 16 + lr][lg * 8];
#pragma unroll
    for (int fn = 0; fn < 6; ++fn)
      bfv[fn] = *(const short8*)&Bl[wn * 96 + fn * 16 + lr][lg * 8];
#pragma unroll
    for (int fm = 0; fm < 4; ++fm)
#pragma unroll
      for (int fn = 0; fn < 6; ++fn)
        acc[fm][fn] = __builtin_amdgcn_mfma_f32_16x16x32_bf16(af[fm], bfv[fn], acc[fm][fn], 0, 0, 0);
  }
#pragma unroll
  for (int fm = 0; fm < 4; ++fm) {
#pragma unroll
    for (int fn = 0; fn < 6; ++fn) {
      int col = n0 + wn * 96 + fn * 16 + lr;
      float bias;
      if (MODE == 0) bias = (col < 192) ? b0[col] : ((col < 384) ? 0.f : b1[col - 384]);
      else           bias = b0[col];
#pragma unroll
      for (int r = 0; r < 4; ++r) {
        int row = m0 + wm * 64 + fm * 16 + lg * 4 + r;
        float v = acc[fm][fn][r] + bias;
        if (MODE == 1) v = v / (1.f + __expf(-v));   // silu
        out[(size_t)row * NTOT + col] = f2bf(v);
      }
    }
  }
}

// ---------------------------------------------------------------------------
// GEMM with full-row (N=192) tile + LayerNorm + residual epilogue.
// tile 128 x 192, 4 waves (2x2 of 64x96). A is bf16.
// MODE 0: proj  (A = attn_out windowed, scatter via img_pos, resid = x,  out = x1)
// MODE 1: fc2   (A = hmid natural,      direct,              resid = x1, out = d_out)
template<int KTOT, int MODE>
__global__ __launch_bounds__(256) void gemm_ln(
    const ushort_t* __restrict__ Ab, const ushort_t* __restrict__ W,
    const float* __restrict__ bias, const float* __restrict__ gamma,
    const float* __restrict__ beta, const float* __restrict__ resid,
    float* __restrict__ out) {
  __shared__ ushort_t Al[128][32];
  __shared__ ushort_t Bl[192][32];
  __shared__ float part[2][128][2];
  int t = threadIdx.x;
  int m0 = blockIdx.x * 128;
  int arow = t >> 1, akoff = (t & 1) << 4;
  const ushort_t* Arowp = Ab + (size_t)(m0 + arow) * KTOT + akoff;
  int colA = akoff ? 4 : 0;
  int lane = t & 63, wid = t >> 6;
  int wm = wid >> 1, wn = wid & 1;
  int lr = lane & 15, lg = lane >> 4;

  f32x4 acc[4][6];
#pragma unroll
  for (int a = 0; a < 4; ++a)
#pragma unroll
    for (int b = 0; b < 6; ++b) acc[a][b] = (f32x4){0.f, 0.f, 0.f, 0.f};

  for (int kt = 0; kt < KTOT; kt += 32) {
    ushort4 a0 = *(const ushort4*)(Arowp + kt + 0);
    ushort4 a1 = *(const ushort4*)(Arowp + kt + 4);
    ushort4 a2 = *(const ushort4*)(Arowp + kt + 8);
    ushort4 a3 = *(const ushort4*)(Arowp + kt + 12);
    ushort4 bq[3][2];
#pragma unroll
    for (int i = 0; i < 3; ++i) {
      int task = t + (i << 8);
      int bn = task >> 2, c = task & 3;
      const ushort_t* p = W + (size_t)bn * KTOT + kt + (c << 3);
      bq[i][0] = *(const ushort4*)p;
      bq[i][1] = *(const ushort4*)(p + 4);
    }
    __syncthreads();
    ushort_t* Ar = &Al[arow][0];
    *(ushort4*)(Ar + colA +  0) = a0;
    *(ushort4*)(Ar + colA +  8) = a1;
    *(ushort4*)(Ar + colA + 16) = a2;
    *(ushort4*)(Ar + colA + 24) = a3;
#pragma unroll
    for (int i = 0; i < 3; ++i) {
      int task = t + (i << 8);
      int bn = task >> 2, c = task & 3;
      int colB = ((c & 1) << 4) | ((c >> 1) << 2);
      ushort_t* Br = &Bl[bn][0];
      *(ushort4*)(Br + colB + 0) = bq[i][0];
      *(ushort4*)(Br + colB + 8) = bq[i][1];
    }
    __syncthreads();
    short8 af[4], bfv[6];
#pragma unroll
    for (int fm = 0; fm < 4; ++fm)
      af[fm] = *(const short8*)&Al[wm * 64 + fm * 16 + lr][lg * 8];
#pragma unroll
    for (int fn = 0; fn < 6; ++fn)
      bfv[fn] = *(const short8*)&Bl[wn * 96 + fn * 16 + lr][lg * 8];
#pragma unroll
    for (int fm = 0; fm < 4; ++fm)
#pragma unroll
      for (int fn = 0; fn < 6; ++fn)
        acc[fm][fn] = __builtin_amdgcn_mfma_f32_16x16x32_bf16(af[fm], bfv[fn], acc[fm][fn], 0, 0, 0);
  }
  // bias add + per-row LN partials (each wave covers 96 of 192 cols)
#pragma unroll
  for (int fm = 0; fm < 4; ++fm) {
#pragma unroll
    for (int r = 0; r < 4; ++r) {
      float s1 = 0.f, s2 = 0.f;
#pragma unroll
      for (int fn = 0; fn < 6; ++fn) {
        int col = wn * 96 + fn * 16 + lr;
        float v = acc[fm][fn][r] + bias[col];
        acc[fm][fn][r] = v;
        s1 += v; s2 += v * v;
      }
#pragma unroll
      for (int off = 1; off < 16; off <<= 1) {
        s1 += __shfl_xor(s1, off);
        s2 += __shfl_xor(s2, off);
      }
      if (lr == 0) {
        int lrow = wm * 64 + fm * 16 + lg * 4 + r;
        part[wn][lrow][0] = s1;
        part[wn][lrow][1] = s2;
      }
    }
  }
  __syncthreads();
#pragma unroll
  for (int fm = 0; fm < 4; ++fm) {
#pragma unroll
    for (int r = 0; r < 4; ++r) {
      int lrow = wm * 64 + fm * 16 + lg * 4 + r;
      float s1 = part[0][lrow][0] + part[1][lrow][0];
      float s2 = part[0][lrow][1] + part[1][lrow][1];
      float mean = s1 * (1.f / 192.f);
      float var  = s2 * (1.f / 192.f) - mean * mean;
      float rstd = rsqrtf(fmaxf(var, 0.f) + 1e-5f);
      int row = m0 + lrow;
      size_t obase = (MODE == 0) ? (size_t)img_pos(row) * 192 : (size_t)row * 192;
#pragma unroll
      for (int fn = 0; fn < 6; ++fn) {
        int col = wn * 96 + fn * 16 + lr;
        float v = acc[fm][fn][r];
        out[obase + col] = resid[obase + col] + (v - mean) * rstd * gamma[col] + beta[col];
      }
    }
  }
}

// ---------------------------------------------------------------------------
// Attention v2: block = (window, head), 256 threads. thread = (q = t/4, c = t%4).
// Lane owns dims [c*8, c*8+8) of its query row; keys partitioned j = 4*jj + c
// (full 32-dot per key, no per-key shuffles). P shared via LDS ps[49][49].
__global__ __launch_bounds__(256) void attn_kernel(
    const ushort_t* __restrict__ qkv, const float* __restrict__ logit_scale,
    const float* __restrict__ tab_s, ushort_t* __restrict__ attn_out) {
  __shared__ float ks[49][36];
  __shared__ float vs[49][36];
  __shared__ float ps[49][49];
  __shared__ float tab_l[169];
  int win = blockIdx.x, head = blockIdx.y;
  int t = threadIdx.x;
  int q = t >> 2, c = t & 3;
  int qr = q < 49 ? q : 48;
  int wi = win & 63;
  int wh0 = (wi >> 3) * 7, ww0 = (wi & 7) * 7;

  for (int u = t; u < 169; u += 256) tab_l[u] = tab_s[u * 6 + head];

  size_t base = (size_t)win * 49 * 576 + head * 32;
  if (t < 196) {                       // stage K,V: 49 rows x 4 chunks of 8
    int r = t >> 2, cc = t & 3;
    const ushort_t* kp = qkv + base + (size_t)r * 576 + 192 + cc * 8;
    ushort4 k0 = *(const ushort4*)kp,         k1 = *(const ushort4*)(kp + 4);
    ushort4 v0 = *(const ushort4*)(kp + 192), v1 = *(const ushort4*)(kp + 196);
    float* kr = &ks[r][cc * 8];
    kr[0] = bf2f(k0.x); kr[1] = bf2f(k0.y); kr[2] = bf2f(k0.z); kr[3] = bf2f(k0.w);
    kr[4] = bf2f(k1.x); kr[5] = bf2f(k1.y); kr[6] = bf2f(k1.z); kr[7] = bf2f(k1.w);
    float* vr = &vs[r][cc * 8];
    vr[0] = bf2f(v0.x); vr[1] = bf2f(v0.y); vr[2] = bf2f(v0.z); vr[3] = bf2f(v0.w);
    vr[4] = bf2f(v1.x); vr[5] = bf2f(v1.y); vr[6] = bf2f(v1.z); vr[7] = bf2f(v1.w);
  }

  // Q full row in registers (4x redundant across c-lanes; L1 serves it)
  float qv[32];
  {
    const ushort_t* qp = qkv + base + (size_t)qr * 576;
#pragma unroll
    for (int c8 = 0; c8 < 4; ++c8) {
      ushort4 a = *(const ushort4*)(qp + c8 * 8);
      ushort4 b = *(const ushort4*)(qp + c8 * 8 + 4);
      qv[c8 * 8 + 0] = bf2f(a.x); qv[c8 * 8 + 1] = bf2f(a.y);
      qv[c8 * 8 + 2] = bf2f(a.z); qv[c8 * 8 + 3] = bf2f(a.w);
      qv[c8 * 8 + 4] = bf2f(b.x); qv[c8 * 8 + 5] = bf2f(b.y);
      qv[c8 * 8 + 6] = bf2f(b.z); qv[c8 * 8 + 7] = bf2f(b.w);
    }
  }
  float scale = __expf(fminf(logit_scale[head], 4.605170186f));  // ln(100)
  float ssq = 0.f;
#pragma unroll
  for (int d = 0; d < 32; ++d) ssq += qv[d] * qv[d];
  float rq = scale / fmaxf(sqrtf(ssq), 1e-12f);
#pragma unroll
  for (int d = 0; d < 32; ++d) qv[d] *= rq;

  __syncthreads();
  // K rows normalized in place: (q,c) handles dims c*8..+7 of row q
  if (q < 49) {
    float kv[8]; float sk = 0.f;
#pragma unroll
    for (int d = 0; d < 8; ++d) { kv[d] = ks[q][c * 8 + d]; sk += kv[d] * kv[d]; }
    sk += __shfl_xor(sk, 1); sk += __shfl_xor(sk, 2);
    float rk = 1.f / fmaxf(sqrtf(sk), 1e-12f);
#pragma unroll
    for (int d = 0; d < 8; ++d) ks[q][c * 8 + d] = kv[d] * rk;
  }
  __syncthreads();

  int rd = (qr * 9363) >> 16, rm = qr - 7 * rd;
  int gr = region3(wh0 + rd) * 3 + region3(ww0 + rm);

  float s[13];
#pragma unroll
  for (int jj = 0; jj < 13; ++jj) {
    int j = jj * 4 + c;
    if (j < 49) {
      const float* kj = &ks[j][0];
      float a = 0.f;
#pragma unroll
      for (int d = 0; d < 32; ++d) a += qv[d] * kj[d];
      int jd = (j * 9363) >> 16, jm = j - 7 * jd;
      int gj = region3(wh0 + jd) * 3 + region3(ww0 + jm);
      int idx = (rd - jd + 6) * 13 + (rm - jm + 6);
      s[jj] = a + tab_l[idx] + (gr == gj ? 0.f : -100.f);
    } else {
      s[jj] = -1e30f;
    }
  }
  float mx = s[0];
#pragma unroll
  for (int jj = 1; jj < 13; ++jj) mx = fmaxf(mx, s[jj]);
  mx = fmaxf(mx, __shfl_xor(mx, 1));
  mx = fmaxf(mx, __shfl_xor(mx, 2));
  float sum = 0.f;
#pragma unroll
  for (int jj = 0; jj < 13; ++jj) { s[jj] = __expf(s[jj] - mx); sum += s[jj]; }
  sum += __shfl_xor(sum, 1);
  sum += __shfl_xor(sum, 2);
  float rs = 1.f / sum;

  if (q < 49) {
#pragma unroll
    for (int jj = 0; jj < 13; ++jj) {
      int j = jj * 4 + c;
      if (j < 49) ps[q][j] = s[jj];
    }
  }
  __syncthreads();

  float o[8];
#pragma unroll
  for (int d = 0; d < 8; ++d) o[d] = 0.f;
#pragma unroll
  for (int j = 0; j < 49; ++j) {
    float pj = ps[qr][j];
    const float* vj = &vs[j][c * 8];
#pragma unroll
    for (int d = 0; d < 8; ++d) o[d] += pj * vj[d];
  }
  if (q < 49) {
    ushort_t* op = attn_out + ((size_t)win * 49 + q) * 192 + head * 32 + c * 8;
    *(ushort4*)(op + 0) = make_ushort4(f2bf(o[0] * rs), f2bf(o[1] * rs),
                                       f2bf(o[2] * rs), f2bf(o[3] * rs));
    *(ushort4*)(op + 4) = make_ushort4(f2bf(o[4] * rs), f2bf(o[5] * rs),
                                       f2bf(o[6] * rs), f2bf(o[7] * rs));
  }
}

// ---------------------------------------------------------------------------
extern "C" void kernel_launch(void* const* d_in, const int* in_sizes, int n_in,
                              void* d_out, int out_size, void* d_ws, size_t ws_size,
                              hipStream_t stream) {
  (void)in_sizes; (void)n_in; (void)out_size; (void)ws_size;
  const float* x    = (const float*)d_in[0];
  const float* qkvw = (const float*)d_in[1];
  const float* qb   = (const float*)d_in[2];
  const float* vb   = (const float*)d_in[3];
  const float* ls   = (const float*)d_in[4];
  const float* cw1  = (const float*)d_in[5];
  const float* cb1  = (const float*)d_in[6];
  const float* cw2  = (const float*)d_in[7];
  const float* pw   = (const float*)d_in[8];
  const float* pb   = (const float*)d_in[9];
  const float* n1g  = (const float*)d_in[10];
  const float* n1b  = (const float*)d_in[11];
  const float* n2g  = (const float*)d_in[12];
  const float* n2b  = (const float*)d_in[13];
  const float* f1w  = (const float*)d_in[14];
  const float* f1b  = (const float*)d_in[15];
  const float* f2w  = (const float*)d_in[16];
  const float* f2b  = (const float*)d_in[17];
  float* out = (float*)d_out;

  char* ws = (char*)d_ws;
  ushort_t* wq_bf = (ushort_t*)ws;                 // 110592
  ushort_t* wp_bf = wq_bf + 110592;                // 36864
  ushort_t* w1_bf = wp_bf + 36864;                 // 147456
  ushort_t* w2_bf = w1_bf + 147456;                // 147456
  float*    tab_s = (float*)(w2_bf + 147456);      // 1014 floats
  const size_t OFF_BIG = 1 << 20;
  ushort_t* qkv_out = (ushort_t*)(ws + OFF_BIG);                           // 100352*576 bf16
  ushort_t* attn_o  = (ushort_t*)(ws + OFF_BIG + 115605504);               // 100352*192 bf16
  float*    x1      = (float*)   (ws + OFF_BIG + 115605504 + 38535168);    // 100352*192 f32
  ushort_t* hmid    = (ushort_t*)(ws + OFF_BIG);   // reuse qkv+attn: 100352*768 bf16 (exact fit)

  cvt_kernel<<<(110592 + 255) / 256, 256, 0, stream>>>(qkvw, wq_bf, 110592);
  cvt_kernel<<<(36864  + 255) / 256, 256, 0, stream>>>(pw,   wp_bf, 36864);
  cvt_kernel<<<(147456 + 255) / 256, 256, 0, stream>>>(f1w,  w1_bf, 147456);
  cvt_kernel<<<(147456 + 255) / 256, 256, 0, stream>>>(f2w,  w2_bf, 147456);
  cpb_kernel<<<169, 256, 0, stream>>>(cw1, cb1, cw2, tab_s);

  gemm_n192<192, 0><<<dim3(784, 3), 256, 0, stream>>>(x, wq_bf, qb, vb, qkv_out, 576);
  attn_kernel<<<dim3(2048, 6), 256, 0, stream>>>(qkv_out, ls, tab_s, attn_o);
  gemm_ln<192, 0><<<784, 256, 0, stream>>>(attn_o, wp_bf, pb, n1g, n1b, x, x1);
  gemm_n192<192, 1><<<dim3(784, 4), 256, 0, stream>>>(x1, w1_bf, f1b, nullptr, hmid, 768);
  gemm_ln<768, 1><<<784, 256, 0, stream>>>(hmid, w2_bf, f2b, n2g, n2b, x1, out);
}

// Round 3
// 502.007 us; speedup vs baseline: 1.6948x; 1.4603x over previous
//
#include <hip/hip_runtime.h>

// ============================================================================
// Swin V2 block, round 3.
// R2 post-mortem: attn still 318us (VGPR 236 -> occupancy 11.7%, dep-chain
// bound fp32 VALU). Rewrite attention with MFMA (same verified fragment
// layout as the GEMMs): QK^T 4 mfma/wave (K=32 exact), softmax in C/D reg
// layout (16-lane butterfly), P->bf16 k-permuted LDS, PV 4 mfma/wave.
// LDS rows padded to 80B (16B-aligned b128, 20-bank shift -> 2-way max).
// MFMA layout (HW-verified R1/R2): A row=lane%16, k=4*(lane/16)+{0..3}(+16);
// B col=lane%16 same k; C/D col=lane%16, row=4*(lane/16)+reg.
// LDS perm: col = 8*((k%16)/4) + 4*(k/16) + k%4.
// ============================================================================

typedef unsigned short ushort_t;
using f32x4  = __attribute__((ext_vector_type(4))) float;
using short8 = __attribute__((ext_vector_type(8))) short;

__device__ __forceinline__ ushort_t f2bf(float f) {
  union { float f; unsigned u; } v; v.f = f;
  unsigned r = v.u + 0x7fffu + ((v.u >> 16) & 1u);
  return (ushort_t)(r >> 16);
}
__device__ __forceinline__ float bf2f(ushort_t u) {
  union { unsigned u; float f; } v; v.u = ((unsigned)u) << 16;
  return v.f;
}

// windowed-token index m -> image row index (same map for gather and scatter)
__device__ __forceinline__ int img_pos(int m) {
  int win = m / 49, n = m - win * 49;
  int b = win >> 6, wi = win & 63;
  int nd = n / 7, nm = n - nd * 7;
  int hs = (wi >> 3) * 7 + nd;
  int ws = (wi & 7) * 7 + nm;
  int h = hs + 3; if (h >= 56) h -= 56;
  int w = ws + 3; if (w >= 56) w -= 56;
  return b * 3136 + h * 56 + w;
}

__device__ __forceinline__ int region3(int a) { return a < 49 ? 0 : (a < 53 ? 1 : 2); }

// ---------------------------------------------------------------------------
__global__ void cvt_kernel(const float* __restrict__ in, ushort_t* __restrict__ out, int n) {
  int i = blockIdx.x * 256 + threadIdx.x;
  if (i < n) out[i] = f2bf(in[i]);
}

// ---------------------------------------------------------------------------
// CPB: tab_s[head][e] = 16*sigmoid( relu(REL_TABLE[e] @ w1.T + b1) @ w2.T )
__global__ __launch_bounds__(256) void cpb_kernel(
    const float* __restrict__ w1, const float* __restrict__ b1,
    const float* __restrict__ w2, float* __restrict__ tab_s) {
  int e = blockIdx.x;            // 0..168
  int t = threadIdx.x;           // 0..255
  int i = e / 13, j = e - 13 * (e / 13);
  auto cval = [](int a) -> float {
    float r = (a - 6) * (8.0f / 6.0f);
    float v = log2f(fabsf(r) + 1.f) * (1.f / 3.f);
    return r < 0.f ? -v : v;
  };
  float ci = cval(i), cj = cval(j);
  float h = fmaxf(ci * w1[2 * t] + cj * w1[2 * t + 1] + b1[t], 0.f);
  __shared__ float red[256];
  for (int head = 0; head < 6; ++head) {
    red[t] = h * w2[head * 256 + t];
    __syncthreads();
    for (int st = 128; st > 0; st >>= 1) {
      if (t < st) red[t] += red[t + st];
      __syncthreads();
    }
    if (t == 0) tab_s[head * 169 + e] = 16.f / (1.f + __expf(-red[0]));
    __syncthreads();
  }
}

// ---------------------------------------------------------------------------
// GEMM, tile 128(M) x 192(N), K-step 32, 4 waves (2x2 of 64x96), fp32 A + cvt.
template<int KTOT, int MODE>
__global__ __launch_bounds__(256) void gemm_n192(
    const float* __restrict__ Af, const ushort_t* __restrict__ W,
    const float* __restrict__ b0, const float* __restrict__ b1,
    ushort_t* __restrict__ out, int NTOT) {
  __shared__ ushort_t Al[128][32];
  __shared__ ushort_t Bl[192][32];
  int t = threadIdx.x;
  int m0 = blockIdx.x * 128, n0 = blockIdx.y * 192;

  int arow = t >> 1, akoff = (t & 1) << 4;
  int am = m0 + arow;
  const float* Arowp = (MODE == 0) ? (Af + (size_t)img_pos(am) * 192 + akoff)
                                   : (Af + (size_t)am * KTOT + akoff);
  int colA = akoff ? 4 : 0;

  int lane = t & 63, wid = t >> 6;
  int wm = wid >> 1, wn = wid & 1;
  int lr = lane & 15, lg = lane >> 4;

  f32x4 acc[4][6];
#pragma unroll
  for (int a = 0; a < 4; ++a)
#pragma unroll
    for (int b = 0; b < 6; ++b) acc[a][b] = (f32x4){0.f, 0.f, 0.f, 0.f};

  for (int kt = 0; kt < KTOT; kt += 32) {
    float4 a0 = *(const float4*)(Arowp + kt + 0);
    float4 a1 = *(const float4*)(Arowp + kt + 4);
    float4 a2 = *(const float4*)(Arowp + kt + 8);
    float4 a3 = *(const float4*)(Arowp + kt + 12);
    ushort4 bq[3][2];
#pragma unroll
    for (int i = 0; i < 3; ++i) {
      int task = t + (i << 8);
      int bn = task >> 2, c = task & 3;
      const ushort_t* p = W + (size_t)(n0 + bn) * KTOT + kt + (c << 3);
      bq[i][0] = *(const ushort4*)p;
      bq[i][1] = *(const ushort4*)(p + 4);
    }
    __syncthreads();
    ushort_t* Ar = &Al[arow][0];
    *(ushort4*)(Ar + colA +  0) = make_ushort4(f2bf(a0.x), f2bf(a0.y), f2bf(a0.z), f2bf(a0.w));
    *(ushort4*)(Ar + colA +  8) = make_ushort4(f2bf(a1.x), f2bf(a1.y), f2bf(a1.z), f2bf(a1.w));
    *(ushort4*)(Ar + colA + 16) = make_ushort4(f2bf(a2.x), f2bf(a2.y), f2bf(a2.z), f2bf(a2.w));
    *(ushort4*)(Ar + colA + 24) = make_ushort4(f2bf(a3.x), f2bf(a3.y), f2bf(a3.z), f2bf(a3.w));
#pragma unroll
    for (int i = 0; i < 3; ++i) {
      int task = t + (i << 8);
      int bn = task >> 2, c = task & 3;
      int colB = ((c & 1) << 4) | ((c >> 1) << 2);
      ushort_t* Br = &Bl[bn][0];
      *(ushort4*)(Br + colB + 0) = bq[i][0];
      *(ushort4*)(Br + colB + 8) = bq[i][1];
    }
    __syncthreads();
    short8 af[4], bfv[6];
#pragma unroll
    for (int fm = 0; fm < 4; ++fm)
      af[fm] = *(const short8*)&Al[wm * 64 + fm * 16 + lr][lg * 8];
#pragma unroll
    for (int fn = 0; fn < 6; ++fn)
      bfv[fn] = *(const short8*)&Bl[wn * 96 + fn * 16 + lr][lg * 8];
#pragma unroll
    for (int fm = 0; fm < 4; ++fm)
#pragma unroll
      for (int fn = 0; fn < 6; ++fn)
        acc[fm][fn] = __builtin_amdgcn_mfma_f32_16x16x32_bf16(af[fm], bfv[fn], acc[fm][fn], 0, 0, 0);
  }
#pragma unroll
  for (int fm = 0; fm < 4; ++fm) {
#pragma unroll
    for (int fn = 0; fn < 6; ++fn) {
      int col = n0 + wn * 96 + fn * 16 + lr;
      float bias;
      if (MODE == 0) bias = (col < 192) ? b0[col] : ((col < 384) ? 0.f : b1[col - 384]);
      else           bias = b0[col];
#pragma unroll
      for (int r = 0; r < 4; ++r) {
        int row = m0 + wm * 64 + fm * 16 + lg * 4 + r;
        float v = acc[fm][fn][r] + bias;
        if (MODE == 1) v = v / (1.f + __expf(-v));   // silu
        out[(size_t)row * NTOT + col] = f2bf(v);
      }
    }
  }
}

// ---------------------------------------------------------------------------
// GEMM with full-row (N=192) tile + LayerNorm + residual epilogue.
template<int KTOT, int MODE>
__global__ __launch_bounds__(256) void gemm_ln(
    const ushort_t* __restrict__ Ab, const ushort_t* __restrict__ W,
    const float* __restrict__ bias, const float* __restrict__ gamma,
    const float* __restrict__ beta, const float* __restrict__ resid,
    float* __restrict__ out) {
  __shared__ ushort_t Al[128][32];
  __shared__ ushort_t Bl[192][32];
  __shared__ float part[2][128][2];
  int t = threadIdx.x;
  int m0 = blockIdx.x * 128;
  int arow = t >> 1, akoff = (t & 1) << 4;
  const ushort_t* Arowp = Ab + (size_t)(m0 + arow) * KTOT + akoff;
  int colA = akoff ? 4 : 0;
  int lane = t & 63, wid = t >> 6;
  int wm = wid >> 1, wn = wid & 1;
  int lr = lane & 15, lg = lane >> 4;

  f32x4 acc[4][6];
#pragma unroll
  for (int a = 0; a < 4; ++a)
#pragma unroll
    for (int b = 0; b < 6; ++b) acc[a][b] = (f32x4){0.f, 0.f, 0.f, 0.f};

  for (int kt = 0; kt < KTOT; kt += 32) {
    ushort4 a0 = *(const ushort4*)(Arowp + kt + 0);
    ushort4 a1 = *(const ushort4*)(Arowp + kt + 4);
    ushort4 a2 = *(const ushort4*)(Arowp + kt + 8);
    ushort4 a3 = *(const ushort4*)(Arowp + kt + 12);
    ushort4 bq[3][2];
#pragma unroll
    for (int i = 0; i < 3; ++i) {
      int task = t + (i << 8);
      int bn = task >> 2, c = task & 3;
      const ushort_t* p = W + (size_t)bn * KTOT + kt + (c << 3);
      bq[i][0] = *(const ushort4*)p;
      bq[i][1] = *(const ushort4*)(p + 4);
    }
    __syncthreads();
    ushort_t* Ar = &Al[arow][0];
    *(ushort4*)(Ar + colA +  0) = a0;
    *(ushort4*)(Ar + colA +  8) = a1;
    *(ushort4*)(Ar + colA + 16) = a2;
    *(ushort4*)(Ar + colA + 24) = a3;
#pragma unroll
    for (int i = 0; i < 3; ++i) {
      int task = t + (i << 8);
      int bn = task >> 2, c = task & 3;
      int colB = ((c & 1) << 4) | ((c >> 1) << 2);
      ushort_t* Br = &Bl[bn][0];
      *(ushort4*)(Br + colB + 0) = bq[i][0];
      *(ushort4*)(Br + colB + 8) = bq[i][1];
    }
    __syncthreads();
    short8 af[4], bfv[6];
#pragma unroll
    for (int fm = 0; fm < 4; ++fm)
      af[fm] = *(const short8*)&Al[wm * 64 + fm * 16 + lr][lg * 8];
#pragma unroll
    for (int fn = 0; fn < 6; ++fn)
      bfv[fn] = *(const short8*)&Bl[wn * 96 + fn * 16 + lr][lg * 8];
#pragma unroll
    for (int fm = 0; fm < 4; ++fm)
#pragma unroll
      for (int fn = 0; fn < 6; ++fn)
        acc[fm][fn] = __builtin_amdgcn_mfma_f32_16x16x32_bf16(af[fm], bfv[fn], acc[fm][fn], 0, 0, 0);
  }
#pragma unroll
  for (int fm = 0; fm < 4; ++fm) {
#pragma unroll
    for (int r = 0; r < 4; ++r) {
      float s1 = 0.f, s2 = 0.f;
#pragma unroll
      for (int fn = 0; fn < 6; ++fn) {
        int col = wn * 96 + fn * 16 + lr;
        float v = acc[fm][fn][r] + bias[col];
        acc[fm][fn][r] = v;
        s1 += v; s2 += v * v;
      }
#pragma unroll
      for (int off = 1; off < 16; off <<= 1) {
        s1 += __shfl_xor(s1, off);
        s2 += __shfl_xor(s2, off);
      }
      if (lr == 0) {
        int lrow = wm * 64 + fm * 16 + lg * 4 + r;
        part[wn][lrow][0] = s1;
        part[wn][lrow][1] = s2;
      }
    }
  }
  __syncthreads();
#pragma unroll
  for (int fm = 0; fm < 4; ++fm) {
#pragma unroll
    for (int r = 0; r < 4; ++r) {
      int lrow = wm * 64 + fm * 16 + lg * 4 + r;
      float s1 = part[0][lrow][0] + part[1][lrow][0];
      float s2 = part[0][lrow][1] + part[1][lrow][1];
      float mean = s1 * (1.f / 192.f);
      float var  = s2 * (1.f / 192.f) - mean * mean;
      float rstd = rsqrtf(fmaxf(var, 0.f) + 1e-5f);
      int row = m0 + lrow;
      size_t obase = (MODE == 0) ? (size_t)img_pos(row) * 192 : (size_t)row * 192;
#pragma unroll
      for (int fn = 0; fn < 6; ++fn) {
        int col = wn * 96 + fn * 16 + lr;
        float v = acc[fm][fn][r];
        out[obase + col] = resid[obase + col] + (v - mean) * rstd * gamma[col] + beta[col];
      }
    }
  }
}

// ---------------------------------------------------------------------------
// Attention v3 (MFMA): block = (window, head), 256 threads = 4 waves.
// Wave w owns query rows 16w..16w+15. QK^T: 4 mfma (K=32 exact). Softmax in
// C/D layout (row = 16w+4*lg+r, col = 16fn+lr), 16-lane butterflies.
// P -> bf16 k-permuted LDS; PV: 4 mfma vs transposed+permuted V.
__global__ __launch_bounds__(256) void attn_kernel(
    const ushort_t* __restrict__ qkv, const float* __restrict__ logit_scale,
    const float* __restrict__ tab_s, ushort_t* __restrict__ attn_out) {
  __shared__ ushort_t qs[64][40];   // rows 80B: 16B-aligned, 20-bank shift
  __shared__ ushort_t ksl[64][40];
  __shared__ ushort_t vsl[32][80];  // [dim][perm(key)], rows 160B
  __shared__ ushort_t ps[64][80];
  __shared__ float tab_l[169];
  int win = blockIdx.x, head = blockIdx.y;
  int t = threadIdx.x;
  int wi = win & 63;
  int wh0 = (wi >> 3) * 7, ww0 = (wi & 7) * 7;
  size_t base = (size_t)win * 49 * 576 + head * 32;

  for (int u = t; u < 169; u += 256) tab_l[u] = tab_s[head * 169 + u];

  // zero qs/ks rows 49..63 (cols 0..31; pad never read)
  for (int u = t; u < 240; u += 256) {
    int arr = u / 120, v = u - arr * 120;
    int r = 49 + (v >> 3), c4 = (v & 7) << 2;
    ushort_t* p = arr ? &ksl[r][c4] : &qs[r][c4];
    *(ushort4*)p = make_ushort4(0, 0, 0, 0);
  }

  // V transpose staging: vsl[dim][32*(key/32) + perm32(key%32)], zero key>=49
  for (int u = t; u < 2048; u += 256) {
    int key = u >> 5, d = u & 31;
    ushort_t val = 0;
    if (key < 49) val = qkv[base + (size_t)key * 576 + 384 + d];
    int kk = key & 31;
    int pc = ((key >> 5) << 5) + 8 * ((kk >> 2) & 3) + 4 * (kk >> 4) + (kk & 3);
    vsl[d][pc] = val;
  }

  float scale = __expf(fminf(logit_scale[head], 4.605170186f));  // ln(100)

  // Q/K staging + normalization: task = (row r, quarter c of 8 dims)
  if (t < 196) {
    int r = t >> 2, c = t & 3;
    const ushort_t* qp = qkv + base + (size_t)r * 576 + c * 8;
    ushort4 qa = *(const ushort4*)qp,         qb = *(const ushort4*)(qp + 4);
    ushort4 ka = *(const ushort4*)(qp + 192), kb = *(const ushort4*)(qp + 196);
    float qf[8] = {bf2f(qa.x), bf2f(qa.y), bf2f(qa.z), bf2f(qa.w),
                   bf2f(qb.x), bf2f(qb.y), bf2f(qb.z), bf2f(qb.w)};
    float kf[8] = {bf2f(ka.x), bf2f(ka.y), bf2f(ka.z), bf2f(ka.w),
                   bf2f(kb.x), bf2f(kb.y), bf2f(kb.z), bf2f(kb.w)};
    float sq = 0.f, sk = 0.f;
#pragma unroll
    for (int d = 0; d < 8; ++d) { sq += qf[d] * qf[d]; sk += kf[d] * kf[d]; }
    sq += __shfl_xor(sq, 1); sq += __shfl_xor(sq, 2);
    sk += __shfl_xor(sk, 1); sk += __shfl_xor(sk, 2);
    float rq = scale / fmaxf(sqrtf(sq), 1e-12f);
    float rk = 1.f   / fmaxf(sqrtf(sk), 1e-12f);
    int c0 = ((c & 1) << 4) | ((c >> 1) << 2);   // {0,16,4,20}
    ushort_t* qd = &qs[r][c0];
    *(ushort4*)(qd + 0) = make_ushort4(f2bf(qf[0]*rq), f2bf(qf[1]*rq), f2bf(qf[2]*rq), f2bf(qf[3]*rq));
    *(ushort4*)(qd + 8) = make_ushort4(f2bf(qf[4]*rq), f2bf(qf[5]*rq), f2bf(qf[6]*rq), f2bf(qf[7]*rq));
    ushort_t* kd = &ksl[r][c0];
    *(ushort4*)(kd + 0) = make_ushort4(f2bf(kf[0]*rk), f2bf(kf[1]*rk), f2bf(kf[2]*rk), f2bf(kf[3]*rk));
    *(ushort4*)(kd + 8) = make_ushort4(f2bf(kf[4]*rk), f2bf(kf[5]*rk), f2bf(kf[6]*rk), f2bf(kf[7]*rk));
  }
  __syncthreads();

  int lane = t & 63, w = t >> 6;
  int lr = lane & 15, lg = lane >> 4;

  // QK^T
  short8 aq = *(const short8*)&qs[w * 16 + lr][lg * 8];
  f32x4 acc[4];
#pragma unroll
  for (int fn = 0; fn < 4; ++fn) {
    acc[fn] = (f32x4){0.f, 0.f, 0.f, 0.f};
    short8 bk = *(const short8*)&ksl[fn * 16 + lr][lg * 8];
    acc[fn] = __builtin_amdgcn_mfma_f32_16x16x32_bf16(aq, bk, acc[fn], 0, 0, 0);
  }

  // bias + mask + softmax, rows 16w+4lg+r
  float rsum[4];
#pragma unroll
  for (int r = 0; r < 4; ++r) {
    int row = w * 16 + lg * 4 + r;
    int rd = (row * 9363) >> 16, rm = row - 7 * rd;
    int gr = region3(wh0 + rd) * 3 + region3(ww0 + rm);
    bool rv = row < 49;
    float sv[4];
#pragma unroll
    for (int fn = 0; fn < 4; ++fn) {
      int col = fn * 16 + lr;
      int jd = (col * 9363) >> 16, jm = col - 7 * jd;
      int gj = region3(wh0 + jd) * 3 + region3(ww0 + jm);
      bool cv = rv && (col < 49);
      int idx = cv ? (rd - jd + 6) * 13 + (rm - jm + 6) : 0;
      float s = acc[fn][r] + tab_l[idx] + (gr == gj ? 0.f : -100.f);
      sv[fn] = cv ? s : -1e30f;
    }
    float m = fmaxf(fmaxf(sv[0], sv[1]), fmaxf(sv[2], sv[3]));
#pragma unroll
    for (int o = 1; o < 16; o <<= 1) m = fmaxf(m, __shfl_xor(m, o));
    float sum = 0.f;
#pragma unroll
    for (int fn = 0; fn < 4; ++fn) {
      float e = __expf(sv[fn] - m);
      sum += e;
      int pc = ((fn >> 1) << 5) + 8 * (lr >> 2) + ((fn & 1) << 2) + (lr & 3);
      ps[row][pc] = f2bf(e);
    }
#pragma unroll
    for (int o = 1; o < 16; o <<= 1) sum += __shfl_xor(sum, o);
    rsum[r] = 1.f / sum;
  }
  __syncthreads();

  // PV: out[q][dim] = sum_key P[q][key] V[key][dim]
  short8 ap0 = *(const short8*)&ps[w * 16 + lr][lg * 8];
  short8 ap1 = *(const short8*)&ps[w * 16 + lr][32 + lg * 8];
  f32x4 o2[2];
#pragma unroll
  for (int f = 0; f < 2; ++f) {
    o2[f] = (f32x4){0.f, 0.f, 0.f, 0.f};
    short8 bv0 = *(const short8*)&vsl[f * 16 + lr][lg * 8];
    short8 bv1 = *(const short8*)&vsl[f * 16 + lr][32 + lg * 8];
    o2[f] = __builtin_amdgcn_mfma_f32_16x16x32_bf16(ap0, bv0, o2[f], 0, 0, 0);
    o2[f] = __builtin_amdgcn_mfma_f32_16x16x32_bf16(ap1, bv1, o2[f], 0, 0, 0);
  }
#pragma unroll
  for (int f = 0; f < 2; ++f) {
#pragma unroll
    for (int r = 0; r < 4; ++r) {
      int row = w * 16 + lg * 4 + r;
      if (row < 49)
        attn_out[((size_t)win * 49 + row) * 192 + head * 32 + f * 16 + lr] =
            f2bf(o2[f][r] * rsum[r]);
    }
  }
}

// ---------------------------------------------------------------------------
extern "C" void kernel_launch(void* const* d_in, const int* in_sizes, int n_in,
                              void* d_out, int out_size, void* d_ws, size_t ws_size,
                              hipStream_t stream) {
  (void)in_sizes; (void)n_in; (void)out_size; (void)ws_size;
  const float* x    = (const float*)d_in[0];
  const float* qkvw = (const float*)d_in[1];
  const float* qb   = (const float*)d_in[2];
  const float* vb   = (const float*)d_in[3];
  const float* ls   = (const float*)d_in[4];
  const float* cw1  = (const float*)d_in[5];
  const float* cb1  = (const float*)d_in[6];
  const float* cw2  = (const float*)d_in[7];
  const float* pw   = (const float*)d_in[8];
  const float* pb   = (const float*)d_in[9];
  const float* n1g  = (const float*)d_in[10];
  const float* n1b  = (const float*)d_in[11];
  const float* n2g  = (const float*)d_in[12];
  const float* n2b  = (const float*)d_in[13];
  const float* f1w  = (const float*)d_in[14];
  const float* f1b  = (const float*)d_in[15];
  const float* f2w  = (const float*)d_in[16];
  const float* f2b  = (const float*)d_in[17];
  float* out = (float*)d_out;

  char* ws = (char*)d_ws;
  ushort_t* wq_bf = (ushort_t*)ws;                 // 110592
  ushort_t* wp_bf = wq_bf + 110592;                // 36864
  ushort_t* w1_bf = wp_bf + 36864;                 // 147456
  ushort_t* w2_bf = w1_bf + 147456;                // 147456
  float*    tab_s = (float*)(w2_bf + 147456);      // 6*169 floats
  const size_t OFF_BIG = 1 << 20;
  ushort_t* qkv_out = (ushort_t*)(ws + OFF_BIG);                           // 100352*576 bf16
  ushort_t* attn_o  = (ushort_t*)(ws + OFF_BIG + 115605504);               // 100352*192 bf16
  float*    x1      = (float*)   (ws + OFF_BIG + 115605504 + 38535168);    // 100352*192 f32
  ushort_t* hmid    = (ushort_t*)(ws + OFF_BIG);   // reuse qkv+attn: 100352*768 bf16 (exact fit)

  cvt_kernel<<<(110592 + 255) / 256, 256, 0, stream>>>(qkvw, wq_bf, 110592);
  cvt_kernel<<<(36864  + 255) / 256, 256, 0, stream>>>(pw,   wp_bf, 36864);
  cvt_kernel<<<(147456 + 255) / 256, 256, 0, stream>>>(f1w,  w1_bf, 147456);
  cvt_kernel<<<(147456 + 255) / 256, 256, 0, stream>>>(f2w,  w2_bf, 147456);
  cpb_kernel<<<169, 256, 0, stream>>>(cw1, cb1, cw2, tab_s);

  gemm_n192<192, 0><<<dim3(784, 3), 256, 0, stream>>>(x, wq_bf, qb, vb, qkv_out, 576);
  attn_kernel<<<dim3(2048, 6), 256, 0, stream>>>(qkv_out, ls, tab_s, attn_o);
  gemm_ln<192, 0><<<784, 256, 0, stream>>>(attn_o, wp_bf, pb, n1g, n1b, x, x1);
  gemm_n192<192, 1><<<dim3(784, 4), 256, 0, stream>>>(x1, w1_bf, f1b, nullptr, hmid, 768);
  gemm_ln<768, 1><<<784, 256, 0, stream>>>(hmid, w2_bf, f2b, n2g, n2b, x1, out);
}

// Round 4
// 467.582 us; speedup vs baseline: 1.8196x; 1.0736x over previous
//
#include <hip/hip_runtime.h>

// ============================================================================
// Swin V2 block, round 4.
// R3 post-mortem: gemm_ln 146us x2, SQ_LDS_BANK_CONFLICT 8.4M -> [rows][32]
// LDS tiles are an 8-way bank conflict on ds_read_b128 (64B row stride).
// Changes: (1) all GEMM LDS tiles padded to 40-short rows (80B, uniform
// banks). (2) activations bf16 end-to-end: gather_cvt pre-gathers shifted
// windows from x -> xw_bf; proj writes x1 as bf16 only (fc1 A + fc2 resid).
// MFMA layout (HW-verified): A row=lane%16, k=4*(lane/16)+{0..3}(+16);
// C/D col=lane%16, row=4*(lane/16)+reg. LDS perm col=8*((k%16)/4)+4*(k/16)+k%4.
// ============================================================================

typedef unsigned short ushort_t;
using f32x4  = __attribute__((ext_vector_type(4))) float;
using short8 = __attribute__((ext_vector_type(8))) short;

__device__ __forceinline__ ushort_t f2bf(float f) {
  union { float f; unsigned u; } v; v.f = f;
  unsigned r = v.u + 0x7fffu + ((v.u >> 16) & 1u);
  return (ushort_t)(r >> 16);
}
__device__ __forceinline__ float bf2f(ushort_t u) {
  union { unsigned u; float f; } v; v.u = ((unsigned)u) << 16;
  return v.f;
}

// windowed-token index m -> image row index (same map for gather and scatter)
__device__ __forceinline__ int img_pos(int m) {
  int win = m / 49, n = m - win * 49;
  int b = win >> 6, wi = win & 63;
  int nd = n / 7, nm = n - nd * 7;
  int hs = (wi >> 3) * 7 + nd;
  int ws = (wi & 7) * 7 + nm;
  int h = hs + 3; if (h >= 56) h -= 56;
  int w = ws + 3; if (w >= 56) w -= 56;
  return b * 3136 + h * 56 + w;
}

__device__ __forceinline__ int region3(int a) { return a < 49 ? 0 : (a < 53 ? 1 : 2); }

// ---------------------------------------------------------------------------
__global__ void cvt_kernel(const float* __restrict__ in, ushort_t* __restrict__ out, int n) {
  int i = blockIdx.x * 256 + threadIdx.x;
  if (i < n) out[i] = f2bf(in[i]);
}

// gather shifted-window rows + convert to bf16: xw[m][c] = bf16(x[img_pos(m)][c])
__global__ __launch_bounds__(256) void gather_cvt_kernel(
    const float* __restrict__ x, ushort_t* __restrict__ xw) {
  int i8 = blockIdx.x * 256 + threadIdx.x;      // 100352*24 tasks of 8 elems
  int m = i8 / 24, c8 = (i8 - m * 24) * 8;
  const float* p = x + (size_t)img_pos(m) * 192 + c8;
  float4 a = *(const float4*)p, b = *(const float4*)(p + 4);
  ushort_t* q = xw + (size_t)m * 192 + c8;
  *(ushort4*)q       = make_ushort4(f2bf(a.x), f2bf(a.y), f2bf(a.z), f2bf(a.w));
  *(ushort4*)(q + 4) = make_ushort4(f2bf(b.x), f2bf(b.y), f2bf(b.z), f2bf(b.w));
}

// ---------------------------------------------------------------------------
// CPB: tab_s[head][e] = 16*sigmoid( relu(REL_TABLE[e] @ w1.T + b1) @ w2.T )
__global__ __launch_bounds__(256) void cpb_kernel(
    const float* __restrict__ w1, const float* __restrict__ b1,
    const float* __restrict__ w2, float* __restrict__ tab_s) {
  int e = blockIdx.x;            // 0..168
  int t = threadIdx.x;           // 0..255
  int i = e / 13, j = e - 13 * (e / 13);
  auto cval = [](int a) -> float {
    float r = (a - 6) * (8.0f / 6.0f);
    float v = log2f(fabsf(r) + 1.f) * (1.f / 3.f);
    return r < 0.f ? -v : v;
  };
  float ci = cval(i), cj = cval(j);
  float h = fmaxf(ci * w1[2 * t] + cj * w1[2 * t + 1] + b1[t], 0.f);
  __shared__ float red[256];
  for (int head = 0; head < 6; ++head) {
    red[t] = h * w2[head * 256 + t];
    __syncthreads();
    for (int st = 128; st > 0; st >>= 1) {
      if (t < st) red[t] += red[t + st];
      __syncthreads();
    }
    if (t == 0) tab_s[head * 169 + e] = 16.f / (1.f + __expf(-red[0]));
    __syncthreads();
  }
}

// ---------------------------------------------------------------------------
// GEMM, tile 128(M) x 192(N), K-step 32, 4 waves (2x2 of 64x96), bf16 A.
// MODE 0: qkv (bias = concat(q_bias,0,v_bias) by global col)
// MODE 1: fc1 (bias b0, silu epilogue)
template<int KTOT, int MODE>
__global__ __launch_bounds__(256) void gemm_n192(
    const ushort_t* __restrict__ Ab, const ushort_t* __restrict__ W,
    const float* __restrict__ b0, const float* __restrict__ b1,
    ushort_t* __restrict__ out, int NTOT) {
  __shared__ ushort_t Al[128][40];
  __shared__ ushort_t Bl[192][40];
  int t = threadIdx.x;
  int m0 = blockIdx.x * 128, n0 = blockIdx.y * 192;

  int arow = t >> 1, akoff = (t & 1) << 4;
  const ushort_t* Arowp = Ab + (size_t)(m0 + arow) * KTOT + akoff;
  int colA = akoff ? 4 : 0;

  int lane = t & 63, wid = t >> 6;
  int wm = wid >> 1, wn = wid & 1;
  int lr = lane & 15, lg = lane >> 4;

  f32x4 acc[4][6];
#pragma unroll
  for (int a = 0; a < 4; ++a)
#pragma unroll
    for (int b = 0; b < 6; ++b) acc[a][b] = (f32x4){0.f, 0.f, 0.f, 0.f};

  for (int kt = 0; kt < KTOT; kt += 32) {
    ushort4 a0 = *(const ushort4*)(Arowp + kt + 0);
    ushort4 a1 = *(const ushort4*)(Arowp + kt + 4);
    ushort4 a2 = *(const ushort4*)(Arowp + kt + 8);
    ushort4 a3 = *(const ushort4*)(Arowp + kt + 12);
    ushort4 bq[3][2];
#pragma unroll
    for (int i = 0; i < 3; ++i) {
      int task = t + (i << 8);
      int bn = task >> 2, c = task & 3;
      const ushort_t* p = W + (size_t)(n0 + bn) * KTOT + kt + (c << 3);
      bq[i][0] = *(const ushort4*)p;
      bq[i][1] = *(const ushort4*)(p + 4);
    }
    __syncthreads();
    ushort_t* Ar = &Al[arow][0];
    *(ushort4*)(Ar + colA +  0) = a0;
    *(ushort4*)(Ar + colA +  8) = a1;
    *(ushort4*)(Ar + colA + 16) = a2;
    *(ushort4*)(Ar + colA + 24) = a3;
#pragma unroll
    for (int i = 0; i < 3; ++i) {
      int task = t + (i << 8);
      int bn = task >> 2, c = task & 3;
      int colB = ((c & 1) << 4) | ((c >> 1) << 2);
      ushort_t* Br = &Bl[bn][0];
      *(ushort4*)(Br + colB + 0) = bq[i][0];
      *(ushort4*)(Br + colB + 8) = bq[i][1];
    }
    __syncthreads();
    short8 af[4], bfv[6];
#pragma unroll
    for (int fm = 0; fm < 4; ++fm)
      af[fm] = *(const short8*)&Al[wm * 64 + fm * 16 + lr][lg * 8];
#pragma unroll
    for (int fn = 0; fn < 6; ++fn)
      bfv[fn] = *(const short8*)&Bl[wn * 96 + fn * 16 + lr][lg * 8];
#pragma unroll
    for (int fm = 0; fm < 4; ++fm)
#pragma unroll
      for (int fn = 0; fn < 6; ++fn)
        acc[fm][fn] = __builtin_amdgcn_mfma_f32_16x16x32_bf16(af[fm], bfv[fn], acc[fm][fn], 0, 0, 0);
  }
#pragma unroll
  for (int fm = 0; fm < 4; ++fm) {
#pragma unroll
    for (int fn = 0; fn < 6; ++fn) {
      int col = n0 + wn * 96 + fn * 16 + lr;
      float bias;
      if (MODE == 0) bias = (col < 192) ? b0[col] : ((col < 384) ? 0.f : b1[col - 384]);
      else           bias = b0[col];
#pragma unroll
      for (int r = 0; r < 4; ++r) {
        int row = m0 + wm * 64 + fm * 16 + lg * 4 + r;
        float v = acc[fm][fn][r] + bias;
        if (MODE == 1) v = v / (1.f + __expf(-v));   // silu
        out[(size_t)row * NTOT + col] = f2bf(v);
      }
    }
  }
}

// ---------------------------------------------------------------------------
// GEMM with full-row (N=192) tile + LayerNorm + residual epilogue. A bf16.
// MODE 0: proj (scatter via img_pos, resid = x fp32, out = x1_bf bf16)
// MODE 1: fc2  (natural order, resid = x1_bf bf16, out = d_out fp32)
template<int KTOT, int MODE>
__global__ __launch_bounds__(256) void gemm_ln(
    const ushort_t* __restrict__ Ab, const ushort_t* __restrict__ W,
    const float* __restrict__ bias, const float* __restrict__ gamma,
    const float* __restrict__ beta, const float* __restrict__ residf,
    const ushort_t* __restrict__ residb, float* __restrict__ outf,
    ushort_t* __restrict__ outb) {
  __shared__ ushort_t Al[128][40];
  __shared__ ushort_t Bl[192][40];
  __shared__ float part[2][128][2];
  int t = threadIdx.x;
  int m0 = blockIdx.x * 128;
  int arow = t >> 1, akoff = (t & 1) << 4;
  const ushort_t* Arowp = Ab + (size_t)(m0 + arow) * KTOT + akoff;
  int colA = akoff ? 4 : 0;
  int lane = t & 63, wid = t >> 6;
  int wm = wid >> 1, wn = wid & 1;
  int lr = lane & 15, lg = lane >> 4;

  f32x4 acc[4][6];
#pragma unroll
  for (int a = 0; a < 4; ++a)
#pragma unroll
    for (int b = 0; b < 6; ++b) acc[a][b] = (f32x4){0.f, 0.f, 0.f, 0.f};

  for (int kt = 0; kt < KTOT; kt += 32) {
    ushort4 a0 = *(const ushort4*)(Arowp + kt + 0);
    ushort4 a1 = *(const ushort4*)(Arowp + kt + 4);
    ushort4 a2 = *(const ushort4*)(Arowp + kt + 8);
    ushort4 a3 = *(const ushort4*)(Arowp + kt + 12);
    ushort4 bq[3][2];
#pragma unroll
    for (int i = 0; i < 3; ++i) {
      int task = t + (i << 8);
      int bn = task >> 2, c = task & 3;
      const ushort_t* p = W + (size_t)bn * KTOT + kt + (c << 3);
      bq[i][0] = *(const ushort4*)p;
      bq[i][1] = *(const ushort4*)(p + 4);
    }
    __syncthreads();
    ushort_t* Ar = &Al[arow][0];
    *(ushort4*)(Ar + colA +  0) = a0;
    *(ushort4*)(Ar + colA +  8) = a1;
    *(ushort4*)(Ar + colA + 16) = a2;
    *(ushort4*)(Ar + colA + 24) = a3;
#pragma unroll
    for (int i = 0; i < 3; ++i) {
      int task = t + (i << 8);
      int bn = task >> 2, c = task & 3;
      int colB = ((c & 1) << 4) | ((c >> 1) << 2);
      ushort_t* Br = &Bl[bn][0];
      *(ushort4*)(Br + colB + 0) = bq[i][0];
      *(ushort4*)(Br + colB + 8) = bq[i][1];
    }
    __syncthreads();
    short8 af[4], bfv[6];
#pragma unroll
    for (int fm = 0; fm < 4; ++fm)
      af[fm] = *(const short8*)&Al[wm * 64 + fm * 16 + lr][lg * 8];
#pragma unroll
    for (int fn = 0; fn < 6; ++fn)
      bfv[fn] = *(const short8*)&Bl[wn * 96 + fn * 16 + lr][lg * 8];
#pragma unroll
    for (int fm = 0; fm < 4; ++fm)
#pragma unroll
      for (int fn = 0; fn < 6; ++fn)
        acc[fm][fn] = __builtin_amdgcn_mfma_f32_16x16x32_bf16(af[fm], bfv[fn], acc[fm][fn], 0, 0, 0);
  }
#pragma unroll
  for (int fm = 0; fm < 4; ++fm) {
#pragma unroll
    for (int r = 0; r < 4; ++r) {
      float s1 = 0.f, s2 = 0.f;
#pragma unroll
      for (int fn = 0; fn < 6; ++fn) {
        int col = wn * 96 + fn * 16 + lr;
        float v = acc[fm][fn][r] + bias[col];
        acc[fm][fn][r] = v;
        s1 += v; s2 += v * v;
      }
#pragma unroll
      for (int off = 1; off < 16; off <<= 1) {
        s1 += __shfl_xor(s1, off);
        s2 += __shfl_xor(s2, off);
      }
      if (lr == 0) {
        int lrow = wm * 64 + fm * 16 + lg * 4 + r;
        part[wn][lrow][0] = s1;
        part[wn][lrow][1] = s2;
      }
    }
  }
  __syncthreads();
#pragma unroll
  for (int fm = 0; fm < 4; ++fm) {
#pragma unroll
    for (int r = 0; r < 4; ++r) {
      int lrow = wm * 64 + fm * 16 + lg * 4 + r;
      float s1 = part[0][lrow][0] + part[1][lrow][0];
      float s2 = part[0][lrow][1] + part[1][lrow][1];
      float mean = s1 * (1.f / 192.f);
      float var  = s2 * (1.f / 192.f) - mean * mean;
      float rstd = rsqrtf(fmaxf(var, 0.f) + 1e-5f);
      int row = m0 + lrow;
      size_t obase = (MODE == 0) ? (size_t)img_pos(row) * 192 : (size_t)row * 192;
#pragma unroll
      for (int fn = 0; fn < 6; ++fn) {
        int col = wn * 96 + fn * 16 + lr;
        float v = (acc[fm][fn][r] - mean) * rstd * gamma[col] + beta[col];
        if (MODE == 0) outb[obase + col] = f2bf(residf[obase + col] + v);
        else           outf[obase + col] = bf2f(residb[obase + col]) + v;
      }
    }
  }
}

// ---------------------------------------------------------------------------
// Attention (MFMA): block = (window, head), 256 threads = 4 waves.
__global__ __launch_bounds__(256) void attn_kernel(
    const ushort_t* __restrict__ qkv, const float* __restrict__ logit_scale,
    const float* __restrict__ tab_s, ushort_t* __restrict__ attn_out) {
  __shared__ ushort_t qs[64][40];   // rows 80B: 16B-aligned, uniform banks
  __shared__ ushort_t ksl[64][40];
  __shared__ ushort_t vsl[32][80];  // [dim][perm(key)], rows 160B
  __shared__ ushort_t ps[64][80];
  __shared__ float tab_l[169];
  int win = blockIdx.x, head = blockIdx.y;
  int t = threadIdx.x;
  int wi = win & 63;
  int wh0 = (wi >> 3) * 7, ww0 = (wi & 7) * 7;
  size_t base = (size_t)win * 49 * 576 + head * 32;

  for (int u = t; u < 169; u += 256) tab_l[u] = tab_s[head * 169 + u];

  // zero qs/ks rows 49..63 (cols 0..31; pad never read)
  for (int u = t; u < 240; u += 256) {
    int arr = u / 120, v = u - arr * 120;
    int r = 49 + (v >> 3), c4 = (v & 7) << 2;
    ushort_t* p = arr ? &ksl[r][c4] : &qs[r][c4];
    *(ushort4*)p = make_ushort4(0, 0, 0, 0);
  }

  // V transpose staging: vsl[dim][32*(key/32) + perm32(key%32)], zero key>=49
  for (int u = t; u < 2048; u += 256) {
    int key = u >> 5, d = u & 31;
    ushort_t val = 0;
    if (key < 49) val = qkv[base + (size_t)key * 576 + 384 + d];
    int kk = key & 31;
    int pc = ((key >> 5) << 5) + 8 * ((kk >> 2) & 3) + 4 * (kk >> 4) + (kk & 3);
    vsl[d][pc] = val;
  }

  float scale = __expf(fminf(logit_scale[head], 4.605170186f));  // ln(100)

  // Q/K staging + normalization: task = (row r, quarter c of 8 dims)
  if (t < 196) {
    int r = t >> 2, c = t & 3;
    const ushort_t* qp = qkv + base + (size_t)r * 576 + c * 8;
    ushort4 qa = *(const ushort4*)qp,         qb = *(const ushort4*)(qp + 4);
    ushort4 ka = *(const ushort4*)(qp + 192), kb = *(const ushort4*)(qp + 196);
    float qf[8] = {bf2f(qa.x), bf2f(qa.y), bf2f(qa.z), bf2f(qa.w),
                   bf2f(qb.x), bf2f(qb.y), bf2f(qb.z), bf2f(qb.w)};
    float kf[8] = {bf2f(ka.x), bf2f(ka.y), bf2f(ka.z), bf2f(ka.w),
                   bf2f(kb.x), bf2f(kb.y), bf2f(kb.z), bf2f(kb.w)};
    float sq = 0.f, sk = 0.f;
#pragma unroll
    for (int d = 0; d < 8; ++d) { sq += qf[d] * qf[d]; sk += kf[d] * kf[d]; }
    sq += __shfl_xor(sq, 1); sq += __shfl_xor(sq, 2);
    sk += __shfl_xor(sk, 1); sk += __shfl_xor(sk, 2);
    float rq = scale / fmaxf(sqrtf(sq), 1e-12f);
    float rk = 1.f   / fmaxf(sqrtf(sk), 1e-12f);
    int c0 = ((c & 1) << 4) | ((c >> 1) << 2);   // {0,16,4,20}
    ushort_t* qd = &qs[r][c0];
    *(ushort4*)(qd + 0) = make_ushort4(f2bf(qf[0]*rq), f2bf(qf[1]*rq), f2bf(qf[2]*rq), f2bf(qf[3]*rq));
    *(ushort4*)(qd + 8) = make_ushort4(f2bf(qf[4]*rq), f2bf(qf[5]*rq), f2bf(qf[6]*rq), f2bf(qf[7]*rq));
    ushort_t* kd = &ksl[r][c0];
    *(ushort4*)(kd + 0) = make_ushort4(f2bf(kf[0]*rk), f2bf(kf[1]*rk), f2bf(kf[2]*rk), f2bf(kf[3]*rk));
    *(ushort4*)(kd + 8) = make_ushort4(f2bf(kf[4]*rk), f2bf(kf[5]*rk), f2bf(kf[6]*rk), f2bf(kf[7]*rk));
  }
  __syncthreads();

  int lane = t & 63, w = t >> 6;
  int lr = lane & 15, lg = lane >> 4;

  // QK^T
  short8 aq = *(const short8*)&qs[w * 16 + lr][lg * 8];
  f32x4 acc[4];
#pragma unroll
  for (int fn = 0; fn < 4; ++fn) {
    acc[fn] = (f32x4){0.f, 0.f, 0.f, 0.f};
    short8 bk = *(const short8*)&ksl[fn * 16 + lr][lg * 8];
    acc[fn] = __builtin_amdgcn_mfma_f32_16x16x32_bf16(aq, bk, acc[fn], 0, 0, 0);
  }

  // bias + mask + softmax, rows 16w+4lg+r
  float rsum[4];
#pragma unroll
  for (int r = 0; r < 4; ++r) {
    int row = w * 16 + lg * 4 + r;
    int rd = (row * 9363) >> 16, rm = row - 7 * rd;
    int gr = region3(wh0 + rd) * 3 + region3(ww0 + rm);
    bool rv = row < 49;
    float sv[4];
#pragma unroll
    for (int fn = 0; fn < 4; ++fn) {
      int col = fn * 16 + lr;
      int jd = (col * 9363) >> 16, jm = col - 7 * jd;
      int gj = region3(wh0 + jd) * 3 + region3(ww0 + jm);
      bool cv = rv && (col < 49);
      int idx = cv ? (rd - jd + 6) * 13 + (rm - jm + 6) : 0;
      float s = acc[fn][r] + tab_l[idx] + (gr == gj ? 0.f : -100.f);
      sv[fn] = cv ? s : -1e30f;
    }
    float m = fmaxf(fmaxf(sv[0], sv[1]), fmaxf(sv[2], sv[3]));
#pragma unroll
    for (int o = 1; o < 16; o <<= 1) m = fmaxf(m, __shfl_xor(m, o));
    float sum = 0.f;
#pragma unroll
    for (int fn = 0; fn < 4; ++fn) {
      float e = __expf(sv[fn] - m);
      sum += e;
      int pc = ((fn >> 1) << 5) + 8 * (lr >> 2) + ((fn & 1) << 2) + (lr & 3);
      ps[row][pc] = f2bf(e);
    }
#pragma unroll
    for (int o = 1; o < 16; o <<= 1) sum += __shfl_xor(sum, o);
    rsum[r] = 1.f / sum;
  }
  __syncthreads();

  // PV: out[q][dim] = sum_key P[q][key] V[key][dim]
  short8 ap0 = *(const short8*)&ps[w * 16 + lr][lg * 8];
  short8 ap1 = *(const short8*)&ps[w * 16 + lr][32 + lg * 8];
  f32x4 o2[2];
#pragma unroll
  for (int f = 0; f < 2; ++f) {
    o2[f] = (f32x4){0.f, 0.f, 0.f, 0.f};
    short8 bv0 = *(const short8*)&vsl[f * 16 + lr][lg * 8];
    short8 bv1 = *(const short8*)&vsl[f * 16 + lr][32 + lg * 8];
    o2[f] = __builtin_amdgcn_mfma_f32_16x16x32_bf16(ap0, bv0, o2[f], 0, 0, 0);
    o2[f] = __builtin_amdgcn_mfma_f32_16x16x32_bf16(ap1, bv1, o2[f], 0, 0, 0);
  }
#pragma unroll
  for (int f = 0; f < 2; ++f) {
#pragma unroll
    for (int r = 0; r < 4; ++r) {
      int row = w * 16 + lg * 4 + r;
      if (row < 49)
        attn_out[((size_t)win * 49 + row) * 192 + head * 32 + f * 16 + lr] =
            f2bf(o2[f][r] * rsum[r]);
    }
  }
}

// ---------------------------------------------------------------------------
extern "C" void kernel_launch(void* const* d_in, const int* in_sizes, int n_in,
                              void* d_out, int out_size, void* d_ws, size_t ws_size,
                              hipStream_t stream) {
  (void)in_sizes; (void)n_in; (void)out_size; (void)ws_size;
  const float* x    = (const float*)d_in[0];
  const float* qkvw = (const float*)d_in[1];
  const float* qb   = (const float*)d_in[2];
  const float* vb   = (const float*)d_in[3];
  const float* ls   = (const float*)d_in[4];
  const float* cw1  = (const float*)d_in[5];
  const float* cb1  = (const float*)d_in[6];
  const float* cw2  = (const float*)d_in[7];
  const float* pw   = (const float*)d_in[8];
  const float* pb   = (const float*)d_in[9];
  const float* n1g  = (const float*)d_in[10];
  const float* n1b  = (const float*)d_in[11];
  const float* n2g  = (const float*)d_in[12];
  const float* n2b  = (const float*)d_in[13];
  const float* f1w  = (const float*)d_in[14];
  const float* f1b  = (const float*)d_in[15];
  const float* f2w  = (const float*)d_in[16];
  const float* f2b  = (const float*)d_in[17];
  float* out = (float*)d_out;

  char* ws = (char*)d_ws;
  ushort_t* wq_bf = (ushort_t*)ws;                 // 110592
  ushort_t* wp_bf = wq_bf + 110592;                // 36864
  ushort_t* w1_bf = wp_bf + 36864;                 // 147456
  ushort_t* w2_bf = w1_bf + 147456;                // 147456
  float*    tab_s = (float*)(w2_bf + 147456);      // 6*169 floats
  const size_t OFF_BIG = 1 << 20;
  // Regions (bytes from OFF_BIG):
  //  R1 [0, 115605504)              qkv_out bf16   | hmid (R1+R2) after attn dead
  //  R2 [115605504, 154140672)      xw_bf then attn_o bf16
  //  R3 [154140672, 192675840)      x1_bf bf16
  ushort_t* qkv_out = (ushort_t*)(ws + OFF_BIG);
  ushort_t* xw_bf   = (ushort_t*)(ws + OFF_BIG + 115605504);
  ushort_t* attn_o  = (ushort_t*)(ws + OFF_BIG + 115605504);
  ushort_t* x1_bf   = (ushort_t*)(ws + OFF_BIG + 154140672);
  ushort_t* hmid    = (ushort_t*)(ws + OFF_BIG);   // 100352*768 bf16 over R1+R2

  cvt_kernel<<<(110592 + 255) / 256, 256, 0, stream>>>(qkvw, wq_bf, 110592);
  cvt_kernel<<<(36864  + 255) / 256, 256, 0, stream>>>(pw,   wp_bf, 36864);
  cvt_kernel<<<(147456 + 255) / 256, 256, 0, stream>>>(f1w,  w1_bf, 147456);
  cvt_kernel<<<(147456 + 255) / 256, 256, 0, stream>>>(f2w,  w2_bf, 147456);
  cpb_kernel<<<169, 256, 0, stream>>>(cw1, cb1, cw2, tab_s);
  gather_cvt_kernel<<<9408, 256, 0, stream>>>(x, xw_bf);

  gemm_n192<192, 0><<<dim3(784, 3), 256, 0, stream>>>(xw_bf, wq_bf, qb, vb, qkv_out, 576);
  attn_kernel<<<dim3(2048, 6), 256, 0, stream>>>(qkv_out, ls, tab_s, attn_o);
  gemm_ln<192, 0><<<784, 256, 0, stream>>>(attn_o, wp_bf, pb, n1g, n1b, x, nullptr, nullptr, x1_bf);
  gemm_n192<192, 1><<<dim3(784, 4), 256, 0, stream>>>(x1_bf, w1_bf, f1b, nullptr, hmid, 768);
  gemm_ln<768, 1><<<784, 256, 0, stream>>>(hmid, w2_bf, f2b, n2g, n2b, nullptr, x1_bf, out, nullptr);
}